// Round 4
// baseline (114.818 us; speedup 1.0000x reference)
//
#include <hip/hip_runtime.h>
#include <cstdint>
#include <cstddef>

typedef unsigned short u16;
typedef __attribute__((ext_vector_type(8))) short bf16x8;
typedef __attribute__((ext_vector_type(4))) float f32x4;

#define DEV __device__ __forceinline__

static constexpr float LOG2E = 1.4426950408889634f;

DEV u16 f2bf(float f) {
  uint32_t u = __float_as_uint(f);
  u += 0x7fffu + ((u >> 16) & 1u);
  return (u16)(u >> 16);
}
DEV float bf2f(u16 h) {
  uint32_t u = ((uint32_t)h) << 16;
  return __uint_as_float(u);
}
// packed f32x2 -> bf16x2 (RNE), single VOP3 instr
DEV uint32_t cvtpk(float lo, float hi) {
  uint32_t r;
  asm("v_cvt_pk_bf16_f32 %0, %1, %2" : "=v"(r) : "v"(lo), "v"(hi));
  return r;
}
// 2^x via v_exp_f32 (native exp2)
DEV float exp2fast(float x) {
  float r;
  asm("v_exp_f32 %0, %1" : "=v"(r) : "v"(x));
  return r;
}

DEV f32x4 mfma16(bf16x8 a, bf16x8 b, f32x4 c) {
  return __builtin_amdgcn_mfma_f32_16x16x32_bf16(a, b, c, 0, 0, 0);
}

// async global->LDS, 16B per lane; lds ptr must be wave-uniform
DEV void gload_lds16(const void* g, void* l) {
  __builtin_amdgcn_global_load_lds(
      (const __attribute__((address_space(1))) uint32_t*)g,
      (__attribute__((address_space(3))) uint32_t*)l, 16, 0, 0);
}

static constexpr int BATCH = 4;
static constexpr int C = 256;    // in/out channels
static constexpr int CI = 128;   // inter channels
static constexpr int N = 4096;   // tokens (64x64)
static constexpr int SPLIT = 4;  // key-range split
static constexpr int KPB = N / SPLIT;  // 1024 keys per block

// ---------------- weight convert (q_w pre-scaled by log2e) -----------------
__global__ __launch_bounds__(256) void cvt_w(const float* __restrict__ a,
                                             const float* __restrict__ b,
                                             const float* __restrict__ c,
                                             const float* __restrict__ d,
                                             u16* __restrict__ oa, u16* __restrict__ ob,
                                             u16* __restrict__ oc, u16* __restrict__ od) {
  int i = blockIdx.x * 256 + threadIdx.x;
  oa[i] = f2bf(a[i] * LOG2E);  // Q weights carry the log2e softmax scale
  ob[i] = f2bf(b[i]);
  oc[i] = f2bf(c[i]);
  od[i] = f2bf(d[i]);
}

// ---------------- QKV projection (512 thr, paired-cvt staging) -------------
__global__ __launch_bounds__(512) void proj_kernel(
    const float* __restrict__ x, const float* __restrict__ rgbd,
    const u16* __restrict__ Wq, const u16* __restrict__ Wk, const u16* __restrict__ Wv,
    const float* __restrict__ qb, const float* __restrict__ kb, const float* __restrict__ vb,
    u16* __restrict__ Qb, u16* __restrict__ Kb, u16* __restrict__ Vtb) {
  __shared__ __align__(16) u16 xT[64][C + 8];
  __shared__ __align__(16) u16 rT[64][C + 8];
  const int b = blockIdx.y;
  const int n0 = blockIdx.x * 64;
  const int t = threadIdx.x;
  {
    const int tok = t & 63, cp = (t >> 6) * 2;  // 8 groups x 2 channels
    const float* xb = x + (size_t)b * C * N + n0;
    const float* rb = rgbd + (size_t)b * C * N + n0;
    for (int c0 = 0; c0 < C; c0 += 16) {
      int c = c0 + cp;
      uint32_t px = cvtpk(xb[(size_t)c * N + tok], xb[(size_t)(c + 1) * N + tok]);
      uint32_t pr = cvtpk(rb[(size_t)c * N + tok], rb[(size_t)(c + 1) * N + tok]);
      *(uint32_t*)&xT[tok][c] = px;
      *(uint32_t*)&rT[tok][c] = pr;
    }
  }
  __syncthreads();
  const int w = t >> 6, lane = t & 63, g = lane >> 4, cl = lane & 15;
  const int tg = w & 3;   // token group (16 tokens)
  const int hf = w >> 2;  // output-half

  // ---- Q (from xT, scaled weights+bias) and K (from rT) ----
#define PROJ_QK(Sarr, W, bias, Out, SCL)                                              \
  {                                                                                   \
    bf16x8 afr[8];                                                                    \
    _Pragma("unroll") for (int ks = 0; ks < 8; ++ks)                                  \
        afr[ks] = *(const bf16x8*)&Sarr[tg * 16 + cl][ks * 32 + g * 8];               \
    _Pragma("unroll") for (int ct = 0; ct < 4; ++ct) {                                \
      const int ctt = hf * 4 + ct;                                                    \
      f32x4 acc = {0.f, 0.f, 0.f, 0.f};                                               \
      _Pragma("unroll") for (int ks = 0; ks < 8; ++ks) {                              \
        bf16x8 bb = *(const bf16x8*)&W[(size_t)(ctt * 16 + cl) * C + ks * 32 + g * 8];\
        acc = mfma16(afr[ks], bb, acc);                                               \
      }                                                                               \
      float bv = bias[ctt * 16 + cl] * (SCL);                                         \
      _Pragma("unroll") for (int r = 0; r < 4; ++r) {                                 \
        int tok = n0 + tg * 16 + g * 4 + r;                                           \
        Out[((size_t)b * N + tok) * CI + ctt * 16 + cl] = f2bf(acc[r] + bv);          \
      }                                                                               \
    }                                                                                 \
  }

  PROJ_QK(xT, Wq, qb, Qb, LOG2E)
  PROJ_QK(rT, Wk, kb, Kb, 1.0f)
#undef PROJ_QK

  // ---- Vt: wave w owns 16 ci rows (w*16..), all 64 tokens ----
  {
    bf16x8 aw[8];
    #pragma unroll
    for (int ks = 0; ks < 8; ++ks)
      aw[ks] = *(const bf16x8*)&Wv[(size_t)(w * 16 + cl) * C + ks * 32 + g * 8];
    #pragma unroll
    for (int ct = 0; ct < 4; ++ct) {
      f32x4 acc = {0.f, 0.f, 0.f, 0.f};
      #pragma unroll
      for (int ks = 0; ks < 8; ++ks) {
        bf16x8 bb = *(const bf16x8*)&rT[ct * 16 + cl][ks * 32 + g * 8];
        acc = mfma16(aw[ks], bb, acc);
      }
      #pragma unroll
      for (int r = 0; r < 4; ++r) {
        int o = w * 16 + g * 4 + r;
        Vtb[((size_t)b * CI + o) * N + n0 + ct * 16 + cl] = f2bf(acc[r] + vb[o]);
      }
    }
  }
}

// ---------------- flash attention (split-K, 32q/wave, 2-phase dbuf) --------
// Grid: 512 blocks (XCD-swizzled). Block = 128 queries x KPB keys; 4 waves,
// each wave owns 32 queries (2 q-tiles). K/V 32-key tiles via global_load_lds
// (source-side XOR swizzle, linear LDS dest). Softmax in exp2-space (Q
// pre-scaled by log2e). Per-wave P re-fragment through small LDS buffer.
__global__ __launch_bounds__(256, 2) void attn_kernel(
    const u16* __restrict__ Qb, const u16* __restrict__ Kb,
    const u16* __restrict__ Vtb, u16* __restrict__ Opart,
    float2* __restrict__ ml) {
  __shared__ __align__(16) u16 Klds[2][32 * 128];
  __shared__ __align__(16) u16 Vlds[2][128 * 32];
  __shared__ __align__(16) u16 Plds[4][2][16][40];
  // XCD swizzle: 512 blocks / 8 XCD = 64 each = 2 full (b,s) groups
  const int lin = blockIdx.x;
  const int nl = (lin & 7) * 64 + (lin >> 3);
  const int qi = nl & 31;
  const int grp = nl >> 5;  // b + 4*s
  const int b = grp & 3;
  const int s = grp >> 2;
  const int q0 = qi * 128;
  const int t = threadIdx.x;
  const int w = t >> 6, lane = t & 63, g = lane >> 4, cl = lane & 15;

  const u16* Kg = Kb + (size_t)b * N * CI;
  const u16* Vg = Vtb + (size_t)b * CI * N;

  // staging source mappings (chunk = 16B), inverse XOR swizzle
  const int k_r = t >> 4;
  const int k_ss = (t & 15) ^ k_r;
  const int v_r = t >> 2;
  const int v_ss = (t & 3) ^ ((t >> 4) & 3);
  const int wbase = (t & ~63);

#define STAGE(bi, k0_)                                                            \
  do {                                                                            \
    _Pragma("unroll") for (int c = 0; c < 2; ++c) {                               \
      gload_lds16(Kg + (size_t)((k0_) + c * 16 + k_r) * CI + k_ss * 8,            \
                  &Klds[bi][(c * 256 + wbase) * 8]);                              \
    }                                                                             \
    _Pragma("unroll") for (int c = 0; c < 2; ++c) {                               \
      gload_lds16(Vg + (size_t)(c * 64 + v_r) * N + (k0_) + v_ss * 8,             \
                  &Vlds[bi][(c * 256 + wbase) * 8]);                              \
    }                                                                             \
  } while (0)

  // hoisted Q B-fragments for both q-tiles (q = cl within tile)
  const u16* Qg = Qb + ((size_t)b * N + q0 + w * 32 + cl) * CI;
  bf16x8 qf[2][4];
  #pragma unroll
  for (int ks = 0; ks < 4; ++ks) {
    qf[0][ks] = *(const bf16x8*)(Qg + ks * 32 + g * 8);
    qf[1][ks] = *(const bf16x8*)(Qg + (size_t)16 * CI + ks * 32 + g * 8);
  }

  f32x4 oacc[2][8];
  #pragma unroll
  for (int qt = 0; qt < 2; ++qt)
    #pragma unroll
    for (int i = 0; i < 8; ++i) oacc[qt][i] = {0.f, 0.f, 0.f, 0.f};
  float m[2] = {-1e30f, -1e30f}, l[2] = {0.f, 0.f};

  const int kbeg = s * KPB, kend = kbeg + KPB;
  STAGE(0, kbeg);
  __syncthreads();

  int buf = 0;
  for (int k0 = kbeg; k0 < kend; k0 += 32) {
    if (k0 + 32 < kend) STAGE(buf ^ 1, k0 + 32);

    // ---- QK^T: S^T[key][q] for both q-tiles ----
    f32x4 st[2][2];
    {
      bf16x8 kf0[4], kf1[4];
      #pragma unroll
      for (int ks = 0; ks < 4; ++ks) {
        kf0[ks] = *(const bf16x8*)&Klds[buf][(cl)*128 + (((ks * 4 + g) ^ cl) & 15) * 8];
        kf1[ks] = *(const bf16x8*)&Klds[buf][(16 + cl) * 128 + (((ks * 4 + g) ^ cl) & 15) * 8];
      }
      f32x4 a00 = {0.f, 0.f, 0.f, 0.f}, a01 = {0.f, 0.f, 0.f, 0.f};
      f32x4 a10 = {0.f, 0.f, 0.f, 0.f}, a11 = {0.f, 0.f, 0.f, 0.f};
      __builtin_amdgcn_s_setprio(1);
      #pragma unroll
      for (int ks = 0; ks < 4; ++ks) {
        a00 = mfma16(kf0[ks], qf[0][ks], a00);
        a01 = mfma16(kf1[ks], qf[0][ks], a01);
        a10 = mfma16(kf0[ks], qf[1][ks], a10);
        a11 = mfma16(kf1[ks], qf[1][ks], a11);
      }
      __builtin_amdgcn_s_setprio(0);
      st[0][0] = a00; st[0][1] = a01;
      st[1][0] = a10; st[1][1] = a11;
    }

    // ---- online softmax per q-tile (exp2-space, defer-max THR=11.5) ----
    #pragma unroll
    for (int qt = 0; qt < 2; ++qt) {
      float tmax = st[qt][0][0];
      #pragma unroll
      for (int ct = 0; ct < 2; ++ct)
        #pragma unroll
        for (int r = 0; r < 4; ++r) tmax = fmaxf(tmax, st[qt][ct][r]);
      tmax = fmaxf(tmax, __shfl_xor(tmax, 16));
      tmax = fmaxf(tmax, __shfl_xor(tmax, 32));
      if (!__all(tmax - m[qt] <= 11.5f)) {
        const float mn = fmaxf(m[qt], tmax);
        const float alpha = exp2fast(m[qt] - mn);
        m[qt] = mn;
        l[qt] *= alpha;
        #pragma unroll
        for (int r = 0; r < 4; ++r) {
          float ar = __shfl(alpha, g * 4 + r);
          #pragma unroll
          for (int ct2 = 0; ct2 < 8; ++ct2) oacc[qt][ct2][r] *= ar;
        }
      }
      float ls = 0.f;
      #pragma unroll
      for (int ct = 0; ct < 2; ++ct) {
        float p0 = exp2fast(st[qt][ct][0] - m[qt]);
        float p1 = exp2fast(st[qt][ct][1] - m[qt]);
        float p2 = exp2fast(st[qt][ct][2] - m[qt]);
        float p3 = exp2fast(st[qt][ct][3] - m[qt]);
        ls += (p0 + p1) + (p2 + p3);
        *(uint32_t*)&Plds[w][qt][cl][ct * 16 + g * 4] = cvtpk(p0, p1);
        *(uint32_t*)&Plds[w][qt][cl][ct * 16 + g * 4 + 2] = cvtpk(p2, p3);
      }
      ls += __shfl_xor(ls, 16);
      ls += __shfl_xor(ls, 32);
      l[qt] += ls;
    }

    // ---- PV: V-frag read once, used by both q-tiles ----
    bf16x8 pa0 = *(const bf16x8*)&Plds[w][0][cl][g * 8];
    bf16x8 pa1 = *(const bf16x8*)&Plds[w][1][cl][g * 8];
    __builtin_amdgcn_s_setprio(1);
    #pragma unroll
    for (int ct2 = 0; ct2 < 8; ++ct2) {
      bf16x8 vfr = *(const bf16x8*)&Vlds[buf][(ct2 * 16 + cl) * 32 + ((g ^ (cl >> 2)) & 3) * 8];
      oacc[0][ct2] = mfma16(pa0, vfr, oacc[0][ct2]);
      oacc[1][ct2] = mfma16(pa1, vfr, oacc[1][ct2]);
    }
    __builtin_amdgcn_s_setprio(0);

    __syncthreads();
    buf ^= 1;
  }
#undef STAGE

  // epilogue: normalized partial O + (m,l) per q-tile
  #pragma unroll
  for (int qt = 0; qt < 2; ++qt) {
    #pragma unroll
    for (int r = 0; r < 4; ++r) {
      float lr = __shfl(l[qt], g * 4 + r);
      float inv = 1.0f / lr;
      const int q = q0 + w * 32 + qt * 16 + g * 4 + r;
      #pragma unroll
      for (int ct2 = 0; ct2 < 8; ++ct2)
        Opart[(((size_t)s * BATCH + b) * N + q) * CI + ct2 * 16 + cl] =
            f2bf(oacc[qt][ct2][r] * inv);
    }
    if (g == 0) {
      const int q = q0 + w * 32 + qt * 16 + cl;
      ml[(size_t)s * BATCH * N + (size_t)b * N + q] = make_float2(m[qt], l[qt]);
    }
  }
}

// ---------------- split-K combine (exp2-space weights) ---------------------
__global__ __launch_bounds__(256) void combine_kernel(
    const u16* __restrict__ Opart, const float2* __restrict__ ml,
    u16* __restrict__ Ob) {
  const int idx = blockIdx.x * 256 + threadIdx.x;  // over B*N*(CI/8)
  const int ci8 = idx & 15;
  const int row = idx >> 4;  // b*N + q
  float2 s0 = ml[row];
  float2 s1 = ml[(size_t)1 * BATCH * N + row];
  float2 s2 = ml[(size_t)2 * BATCH * N + row];
  float2 s3 = ml[(size_t)3 * BATCH * N + row];
  float M = fmaxf(fmaxf(s0.x, s1.x), fmaxf(s2.x, s3.x));
  float w0 = s0.y * exp2fast(s0.x - M);
  float w1 = s1.y * exp2fast(s1.x - M);
  float w2 = s2.y * exp2fast(s2.x - M);
  float w3 = s3.y * exp2fast(s3.x - M);
  float invL = 1.0f / (((w0 + w1) + (w2 + w3)));
  w0 *= invL; w1 *= invL; w2 *= invL; w3 *= invL;
  float acc[8];
  #pragma unroll
  for (int j = 0; j < 8; ++j) acc[j] = 0.f;
  const float ws4[4] = {w0, w1, w2, w3};
  #pragma unroll
  for (int sp = 0; sp < 4; ++sp) {
    bf16x8 v = *(const bf16x8*)&Opart[((size_t)sp * BATCH * N + row) * CI + ci8 * 8];
    #pragma unroll
    for (int j = 0; j < 8; ++j) acc[j] += ws4[sp] * bf2f((u16)v[j]);
  }
  bf16x8 o;
  #pragma unroll
  for (int j = 0; j < 8; ++j) o[j] = (short)f2bf(acc[j]);
  *(bf16x8*)&Ob[(size_t)row * CI + ci8 * 8] = o;
}

// ---------------- output projection + residual (32-token blocks) -----------
__global__ __launch_bounds__(256) void outproj_kernel(
    const u16* __restrict__ Ob, const u16* __restrict__ Wo,
    const float* __restrict__ obias, const float* __restrict__ rgbd,
    float* __restrict__ out) {
  const int b = blockIdx.y;
  const int n0 = blockIdx.x * 32;
  const int t = threadIdx.x;
  const int w = t >> 6, lane = t & 63, g = lane >> 4, cl = lane & 15;

  f32x4 acc[4][2];
  #pragma unroll
  for (int i = 0; i < 4; ++i)
    #pragma unroll
    for (int j = 0; j < 2; ++j) acc[i][j] = {0.f, 0.f, 0.f, 0.f};

  #pragma unroll
  for (int ks = 0; ks < 4; ++ks) {
    bf16x8 bo[2];
    #pragma unroll
    for (int ct = 0; ct < 2; ++ct)
      bo[ct] = *(const bf16x8*)&Ob[((size_t)b * N + n0 + ct * 16 + cl) * CI + ks * 32 + g * 8];
    #pragma unroll
    for (int rt = 0; rt < 4; ++rt) {
      bf16x8 aw = *(const bf16x8*)&Wo[(size_t)(w * 64 + rt * 16 + cl) * CI + ks * 32 + g * 8];
      #pragma unroll
      for (int ct = 0; ct < 2; ++ct) acc[rt][ct] = mfma16(aw, bo[ct], acc[rt][ct]);
    }
  }
  #pragma unroll
  for (int rt = 0; rt < 4; ++rt) {
    #pragma unroll
    for (int r = 0; r < 4; ++r) {
      const int o = w * 64 + rt * 16 + g * 4 + r;
      const float bb = obias[o];
      #pragma unroll
      for (int ct = 0; ct < 2; ++ct) {
        size_t idx = ((size_t)b * C + o) * N + n0 + ct * 16 + cl;
        out[idx] = rgbd[idx] + bb + acc[rt][ct][r];
      }
    }
  }
}

// ---------------- launch ----------------------------------------------------
extern "C" void kernel_launch(void* const* d_in, const int* in_sizes, int n_in,
                              void* d_out, int out_size, void* d_ws, size_t ws_size,
                              hipStream_t stream) {
  (void)in_sizes; (void)n_in; (void)out_size; (void)ws_size;
  const float* rgbd = (const float*)d_in[0];
  const float* x    = (const float*)d_in[1];
  const float* q_w  = (const float*)d_in[2];
  const float* q_b  = (const float*)d_in[3];
  const float* k_w  = (const float*)d_in[4];
  const float* k_b  = (const float*)d_in[5];
  const float* v_w  = (const float*)d_in[6];
  const float* v_b  = (const float*)d_in[7];
  const float* o_w  = (const float*)d_in[8];
  const float* o_b  = (const float*)d_in[9];
  float* out = (float*)d_out;

  char* ws = (char*)d_ws;
  const size_t MB = 1024 * 1024;
  const size_t szQKV = (size_t)BATCH * N * CI * sizeof(u16);  // 4 MB each
  u16* Qb  = (u16*)(ws);                      // 0..4MB (aliased by Ob later)
  u16* Kb  = (u16*)(ws + szQKV);              // 4..8MB
  u16* Vtb = (u16*)(ws + 2 * szQKV);          // 8..12MB
  u16* Wq  = (u16*)(ws + 3 * szQKV);          // 12..12.25MB
  u16* Wk  = Wq + (size_t)CI * C;
  u16* Wv  = Wk + (size_t)CI * C;
  u16* Wo  = Wv + (size_t)CI * C;
  u16* Opart = (u16*)(ws + 13 * MB);          // 13..29MB (SPLIT*4MB)
  float2* ml = (float2*)(ws + 29 * MB);       // 29..29.5MB
  u16* Ob  = Qb;                              // alias: Qb dead after attn

  cvt_w<<<dim3((C * CI) / 256), 256, 0, stream>>>(q_w, k_w, v_w, o_w, Wq, Wk, Wv, Wo);
  proj_kernel<<<dim3(N / 64, BATCH), 512, 0, stream>>>(x, rgbd, Wq, Wk, Wv,
                                                       q_b, k_b, v_b, Qb, Kb, Vtb);
  attn_kernel<<<dim3((N / 128) * BATCH * SPLIT), 256, 0, stream>>>(Qb, Kb, Vtb, Opart, ml);
  combine_kernel<<<dim3(BATCH * N * (CI / 8) / 256), 256, 0, stream>>>(Opart, ml, Ob);
  outproj_kernel<<<dim3(N / 32, BATCH), 256, 0, stream>>>(Ob, Wo, o_b, rgbd, out);
}

// Round 5
// 103.683 us; speedup vs baseline: 1.1074x; 1.1074x over previous
//
#include <hip/hip_runtime.h>
#include <cstdint>
#include <cstddef>

typedef unsigned short u16;
typedef __attribute__((ext_vector_type(8))) short bf16x8;
typedef __attribute__((ext_vector_type(4))) float f32x4;

#define DEV __device__ __forceinline__

static constexpr float LOG2E = 1.4426950408889634f;

DEV u16 f2bf(float f) {
  uint32_t u = __float_as_uint(f);
  u += 0x7fffu + ((u >> 16) & 1u);
  return (u16)(u >> 16);
}
DEV float bf2f(u16 h) {
  uint32_t u = ((uint32_t)h) << 16;
  return __uint_as_float(u);
}
// packed f32x2 -> bf16x2 (RNE), single VOP3 instr
DEV uint32_t cvtpk(float lo, float hi) {
  uint32_t r;
  asm("v_cvt_pk_bf16_f32 %0, %1, %2" : "=v"(r) : "v"(lo), "v"(hi));
  return r;
}
// 2^x via v_exp_f32 (native exp2)
DEV float exp2fast(float x) {
  float r;
  asm("v_exp_f32 %0, %1" : "=v"(r) : "v"(x));
  return r;
}

DEV f32x4 mfma16(bf16x8 a, bf16x8 b, f32x4 c) {
  return __builtin_amdgcn_mfma_f32_16x16x32_bf16(a, b, c, 0, 0, 0);
}

// async global->LDS, 16B per lane; lds ptr must be wave-uniform
DEV void gload_lds16(const void* g, void* l) {
  __builtin_amdgcn_global_load_lds(
      (const __attribute__((address_space(1))) uint32_t*)g,
      (__attribute__((address_space(3))) uint32_t*)l, 16, 0, 0);
}

static constexpr int BATCH = 4;
static constexpr int C = 256;    // in/out channels
static constexpr int CI = 128;   // inter channels
static constexpr int N = 4096;   // tokens (64x64)

// ---------------- weight convert (q_w pre-scaled by log2e) -----------------
__global__ __launch_bounds__(256) void cvt_w(const float* __restrict__ a,
                                             const float* __restrict__ b,
                                             const float* __restrict__ c,
                                             const float* __restrict__ d,
                                             u16* __restrict__ oa, u16* __restrict__ ob,
                                             u16* __restrict__ oc, u16* __restrict__ od) {
  int i = blockIdx.x * 256 + threadIdx.x;
  oa[i] = f2bf(a[i] * LOG2E);  // Q weights carry the log2e softmax scale
  ob[i] = f2bf(b[i]);
  oc[i] = f2bf(c[i]);
  od[i] = f2bf(d[i]);
}

// ---------------- QKV projection (R3 256-thr form + cvtpk staging) ---------
__global__ __launch_bounds__(256) void proj_kernel(
    const float* __restrict__ x, const float* __restrict__ rgbd,
    const u16* __restrict__ Wq, const u16* __restrict__ Wk, const u16* __restrict__ Wv,
    const float* __restrict__ qb, const float* __restrict__ kb, const float* __restrict__ vb,
    u16* __restrict__ Qb, u16* __restrict__ Kb, u16* __restrict__ Vtb) {
  __shared__ __align__(16) u16 xT[64][C + 8];
  __shared__ __align__(16) u16 rT[64][C + 8];
  const int b = blockIdx.y;
  const int n0 = blockIdx.x * 64;
  const int t = threadIdx.x;
  {
    const int tok = t & 63, cp = (t >> 6) * 2;  // 4 slots x 2 paired channels
    const float* xb = x + (size_t)b * C * N + n0;
    const float* rb = rgbd + (size_t)b * C * N + n0;
    for (int c0 = 0; c0 < C; c0 += 8) {
      int c = c0 + cp;
      *(uint32_t*)&xT[tok][c] = cvtpk(xb[(size_t)c * N + tok], xb[(size_t)(c + 1) * N + tok]);
      *(uint32_t*)&rT[tok][c] = cvtpk(rb[(size_t)c * N + tok], rb[(size_t)(c + 1) * N + tok]);
    }
  }
  __syncthreads();
  const int w = t >> 6, lane = t & 63, g = lane >> 4, cl = lane & 15;

#define PROJ_QK(Sarr, W, bias, Out, SCL)                                              \
  {                                                                                   \
    bf16x8 afr[8];                                                                    \
    _Pragma("unroll") for (int ks = 0; ks < 8; ++ks)                                  \
        afr[ks] = *(const bf16x8*)&Sarr[w * 16 + cl][ks * 32 + g * 8];                \
    _Pragma("unroll") for (int ct = 0; ct < 8; ++ct) {                                \
      f32x4 acc = {0.f, 0.f, 0.f, 0.f};                                               \
      _Pragma("unroll") for (int ks = 0; ks < 8; ++ks) {                              \
        bf16x8 bb = *(const bf16x8*)&W[(size_t)(ct * 16 + cl) * C + ks * 32 + g * 8]; \
        acc = mfma16(afr[ks], bb, acc);                                               \
      }                                                                               \
      float bv = bias[ct * 16 + cl] * (SCL);                                          \
      _Pragma("unroll") for (int r = 0; r < 4; ++r) {                                 \
        int tok = n0 + w * 16 + g * 4 + r;                                            \
        Out[((size_t)b * N + tok) * CI + ct * 16 + cl] = f2bf(acc[r] + bv);           \
      }                                                                               \
    }                                                                                 \
  }

  PROJ_QK(xT, Wq, qb, Qb, LOG2E)
  PROJ_QK(rT, Wk, kb, Kb, 1.0f)
#undef PROJ_QK

  #pragma unroll
  for (int rt = 0; rt < 2; ++rt) {
    bf16x8 aw[8];
    #pragma unroll
    for (int ks = 0; ks < 8; ++ks)
      aw[ks] = *(const bf16x8*)&Wv[(size_t)(w * 32 + rt * 16 + cl) * C + ks * 32 + g * 8];
    #pragma unroll
    for (int ct = 0; ct < 4; ++ct) {
      f32x4 acc = {0.f, 0.f, 0.f, 0.f};
      #pragma unroll
      for (int ks = 0; ks < 8; ++ks) {
        bf16x8 bb = *(const bf16x8*)&rT[ct * 16 + cl][ks * 32 + g * 8];
        acc = mfma16(aw[ks], bb, acc);
      }
      #pragma unroll
      for (int r = 0; r < 4; ++r) {
        int o = w * 32 + rt * 16 + g * 4 + r;
        Vtb[((size_t)b * CI + o) * N + n0 + ct * 16 + cl] = f2bf(acc[r] + vb[o]);
      }
    }
  }
}

// ---------------- flash attention (split-K, 32q/wave, 2-phase dbuf) --------
// Grid: 32*B*split blocks (XCD-swizzled, runtime split). Block = 128 queries
// x kpb keys; 4 waves, 32 q each (2 q-tiles). K/V 32-key tiles via
// global_load_lds (source-side XOR swizzle, linear LDS dest). Softmax in
// exp2-space. Plds single-buffered, reused qt0->qt1 (per-wave, no barrier).
__global__ __launch_bounds__(256, 3) void attn_kernel(
    const u16* __restrict__ Qb, const u16* __restrict__ Kb,
    const u16* __restrict__ Vtb, u16* __restrict__ Opart,
    float2* __restrict__ ml, int kpb, int cpx) {
  __shared__ __align__(16) u16 Klds[2][32 * 128];
  __shared__ __align__(16) u16 Vlds[2][128 * 32];
  __shared__ __align__(16) u16 Plds[4][16][40];
  const int lin = blockIdx.x;
  const int nl = (lin & 7) * cpx + (lin >> 3);
  const int qi = nl & 31;
  const int grp = nl >> 5;  // b + 4*s
  const int b = grp & 3;
  const int s = grp >> 2;
  const int q0 = qi * 128;
  const int t = threadIdx.x;
  const int w = t >> 6, lane = t & 63, g = lane >> 4, cl = lane & 15;

  const u16* Kg = Kb + (size_t)b * N * CI;
  const u16* Vg = Vtb + (size_t)b * CI * N;

  // staging source mappings (chunk = 16B), inverse XOR swizzle
  const int k_r = t >> 4;
  const int k_ss = (t & 15) ^ k_r;
  const int v_r = t >> 2;
  const int v_ss = (t & 3) ^ ((t >> 4) & 3);
  const int wbase = (t & ~63);

#define STAGE(bi, k0_)                                                            \
  do {                                                                            \
    _Pragma("unroll") for (int c = 0; c < 2; ++c) {                               \
      gload_lds16(Kg + (size_t)((k0_) + c * 16 + k_r) * CI + k_ss * 8,            \
                  &Klds[bi][(c * 256 + wbase) * 8]);                              \
    }                                                                             \
    _Pragma("unroll") for (int c = 0; c < 2; ++c) {                               \
      gload_lds16(Vg + (size_t)(c * 64 + v_r) * N + (k0_) + v_ss * 8,             \
                  &Vlds[bi][(c * 256 + wbase) * 8]);                              \
    }                                                                             \
  } while (0)

  // hoisted Q B-fragments for both q-tiles (q = cl within tile)
  const u16* Qg = Qb + ((size_t)b * N + q0 + w * 32 + cl) * CI;
  bf16x8 qf[2][4];
  #pragma unroll
  for (int ks = 0; ks < 4; ++ks) {
    qf[0][ks] = *(const bf16x8*)(Qg + ks * 32 + g * 8);
    qf[1][ks] = *(const bf16x8*)(Qg + (size_t)16 * CI + ks * 32 + g * 8);
  }

  f32x4 oacc[2][8];
  #pragma unroll
  for (int qt = 0; qt < 2; ++qt)
    #pragma unroll
    for (int i = 0; i < 8; ++i) oacc[qt][i] = {0.f, 0.f, 0.f, 0.f};
  float m[2] = {-1e30f, -1e30f}, l[2] = {0.f, 0.f};

  const int kbeg = s * kpb, kend = kbeg + kpb;
  STAGE(0, kbeg);
  __syncthreads();

  int buf = 0;
  for (int k0 = kbeg; k0 < kend; k0 += 32) {
    if (k0 + 32 < kend) STAGE(buf ^ 1, k0 + 32);

    // ---- QK^T: S^T[key][q] for both q-tiles ----
    f32x4 st[2][2];
    {
      bf16x8 kf0[4], kf1[4];
      #pragma unroll
      for (int ks = 0; ks < 4; ++ks) {
        kf0[ks] = *(const bf16x8*)&Klds[buf][(cl)*128 + (((ks * 4 + g) ^ cl) & 15) * 8];
        kf1[ks] = *(const bf16x8*)&Klds[buf][(16 + cl) * 128 + (((ks * 4 + g) ^ cl) & 15) * 8];
      }
      f32x4 a00 = {0.f, 0.f, 0.f, 0.f}, a01 = {0.f, 0.f, 0.f, 0.f};
      f32x4 a10 = {0.f, 0.f, 0.f, 0.f}, a11 = {0.f, 0.f, 0.f, 0.f};
      __builtin_amdgcn_s_setprio(1);
      #pragma unroll
      for (int ks = 0; ks < 4; ++ks) {
        a00 = mfma16(kf0[ks], qf[0][ks], a00);
        a01 = mfma16(kf1[ks], qf[0][ks], a01);
        a10 = mfma16(kf0[ks], qf[1][ks], a10);
        a11 = mfma16(kf1[ks], qf[1][ks], a11);
      }
      __builtin_amdgcn_s_setprio(0);
      st[0][0] = a00; st[0][1] = a01;
      st[1][0] = a10; st[1][1] = a11;
    }

    // ---- online softmax per q-tile; Plds reused qt0 -> qt1 ----
    bf16x8 pa[2];
    #pragma unroll
    for (int qt = 0; qt < 2; ++qt) {
      float tmax = st[qt][0][0];
      #pragma unroll
      for (int ct = 0; ct < 2; ++ct)
        #pragma unroll
        for (int r = 0; r < 4; ++r) tmax = fmaxf(tmax, st[qt][ct][r]);
      tmax = fmaxf(tmax, __shfl_xor(tmax, 16));
      tmax = fmaxf(tmax, __shfl_xor(tmax, 32));
      if (!__all(tmax - m[qt] <= 11.5f)) {
        const float mn = fmaxf(m[qt], tmax);
        const float alpha = exp2fast(m[qt] - mn);
        m[qt] = mn;
        l[qt] *= alpha;
        #pragma unroll
        for (int r = 0; r < 4; ++r) {
          float ar = __shfl(alpha, g * 4 + r);
          #pragma unroll
          for (int ct2 = 0; ct2 < 8; ++ct2) oacc[qt][ct2][r] *= ar;
        }
      }
      float ls = 0.f;
      #pragma unroll
      for (int ct = 0; ct < 2; ++ct) {
        float p0 = exp2fast(st[qt][ct][0] - m[qt]);
        float p1 = exp2fast(st[qt][ct][1] - m[qt]);
        float p2 = exp2fast(st[qt][ct][2] - m[qt]);
        float p3 = exp2fast(st[qt][ct][3] - m[qt]);
        ls += (p0 + p1) + (p2 + p3);
        *(uint32_t*)&Plds[w][cl][ct * 16 + g * 4] = cvtpk(p0, p1);
        *(uint32_t*)&Plds[w][cl][ct * 16 + g * 4 + 2] = cvtpk(p2, p3);
      }
      ls += __shfl_xor(ls, 16);
      ls += __shfl_xor(ls, 32);
      l[qt] += ls;
      pa[qt] = *(const bf16x8*)&Plds[w][cl][g * 8];  // read back before qt1 overwrites
    }

    // ---- PV: V-frag read once, used by both q-tiles ----
    __builtin_amdgcn_s_setprio(1);
    #pragma unroll
    for (int ct2 = 0; ct2 < 8; ++ct2) {
      bf16x8 vfr = *(const bf16x8*)&Vlds[buf][(ct2 * 16 + cl) * 32 + ((g ^ (cl >> 2)) & 3) * 8];
      oacc[0][ct2] = mfma16(pa[0], vfr, oacc[0][ct2]);
      oacc[1][ct2] = mfma16(pa[1], vfr, oacc[1][ct2]);
    }
    __builtin_amdgcn_s_setprio(0);

    __syncthreads();
    buf ^= 1;
  }
#undef STAGE

  // epilogue: normalized partial O + (m,l) per q-tile
  #pragma unroll
  for (int qt = 0; qt < 2; ++qt) {
    #pragma unroll
    for (int r = 0; r < 4; ++r) {
      float lr = __shfl(l[qt], g * 4 + r);
      float inv = 1.0f / lr;
      const int q = q0 + w * 32 + qt * 16 + g * 4 + r;
      #pragma unroll
      for (int ct2 = 0; ct2 < 8; ++ct2)
        Opart[(((size_t)(s * BATCH + b)) * N + q) * CI + ct2 * 16 + cl] =
            f2bf(oacc[qt][ct2][r] * inv);
    }
    if (g == 0) {
      const int q = q0 + w * 32 + qt * 16 + cl;
      ml[(size_t)(s * BATCH + b) * N + q] = make_float2(m[qt], l[qt]);
    }
  }
}

// ---------------- split-K combine (compile-time split count) ---------------
template <int NS>
__global__ __launch_bounds__(256) void combine_kernel(
    const u16* __restrict__ Opart, const float2* __restrict__ ml,
    u16* __restrict__ Ob) {
  const int idx = blockIdx.x * 256 + threadIdx.x;  // over B*N*(CI/8)
  const int ci8 = idx & 15;
  const int row = idx >> 4;  // b*N + q
  float2 sv[NS];
  float M = -1e30f;
  #pragma unroll
  for (int sp = 0; sp < NS; ++sp) {
    sv[sp] = ml[(size_t)sp * BATCH * N + row];
    M = fmaxf(M, sv[sp].x);
  }
  float wv[NS], wsum = 0.f;
  #pragma unroll
  for (int sp = 0; sp < NS; ++sp) {
    wv[sp] = sv[sp].y * exp2fast(sv[sp].x - M);
    wsum += wv[sp];
  }
  const float invL = 1.0f / wsum;
  float acc[8];
  #pragma unroll
  for (int j = 0; j < 8; ++j) acc[j] = 0.f;
  #pragma unroll
  for (int sp = 0; sp < NS; ++sp) {
    const float ws = wv[sp] * invL;
    bf16x8 v = *(const bf16x8*)&Opart[((size_t)sp * BATCH * N + row) * CI + ci8 * 8];
    #pragma unroll
    for (int j = 0; j < 8; ++j) acc[j] += ws * bf2f((u16)v[j]);
  }
  bf16x8 o;
  #pragma unroll
  for (int j = 0; j < 8; ++j) o[j] = (short)f2bf(acc[j]);
  *(bf16x8*)&Ob[(size_t)row * CI + ci8 * 8] = o;
}

// ---------------- output projection + residual (R3 64-token form) ----------
__global__ __launch_bounds__(256) void outproj_kernel(
    const u16* __restrict__ Ob, const u16* __restrict__ Wo,
    const float* __restrict__ obias, const float* __restrict__ rgbd,
    float* __restrict__ out) {
  const int b = blockIdx.y;
  const int n0 = blockIdx.x * 64;
  const int t = threadIdx.x;
  const int w = t >> 6, lane = t & 63, g = lane >> 4, cl = lane & 15;

  f32x4 acc[4][4];
  #pragma unroll
  for (int i = 0; i < 4; ++i)
    #pragma unroll
    for (int j = 0; j < 4; ++j) acc[i][j] = {0.f, 0.f, 0.f, 0.f};

  #pragma unroll
  for (int ks = 0; ks < 4; ++ks) {
    bf16x8 bo[4];
    #pragma unroll
    for (int ct = 0; ct < 4; ++ct)
      bo[ct] = *(const bf16x8*)&Ob[((size_t)b * N + n0 + ct * 16 + cl) * CI + ks * 32 + g * 8];
    #pragma unroll
    for (int rt = 0; rt < 4; ++rt) {
      bf16x8 aw = *(const bf16x8*)&Wo[(size_t)(w * 64 + rt * 16 + cl) * CI + ks * 32 + g * 8];
      #pragma unroll
      for (int ct = 0; ct < 4; ++ct) acc[rt][ct] = mfma16(aw, bo[ct], acc[rt][ct]);
    }
  }
  #pragma unroll
  for (int rt = 0; rt < 4; ++rt) {
    #pragma unroll
    for (int r = 0; r < 4; ++r) {
      const int o = w * 64 + rt * 16 + g * 4 + r;
      const float bb = obias[o];
      #pragma unroll
      for (int ct = 0; ct < 4; ++ct) {
        size_t idx = ((size_t)b * C + o) * N + n0 + ct * 16 + cl;
        out[idx] = rgbd[idx] + bb + acc[rt][ct][r];
      }
    }
  }
}

// ---------------- launch ----------------------------------------------------
extern "C" void kernel_launch(void* const* d_in, const int* in_sizes, int n_in,
                              void* d_out, int out_size, void* d_ws, size_t ws_size,
                              hipStream_t stream) {
  (void)in_sizes; (void)n_in; (void)out_size;
  const float* rgbd = (const float*)d_in[0];
  const float* x    = (const float*)d_in[1];
  const float* q_w  = (const float*)d_in[2];
  const float* q_b  = (const float*)d_in[3];
  const float* k_w  = (const float*)d_in[4];
  const float* k_b  = (const float*)d_in[5];
  const float* v_w  = (const float*)d_in[6];
  const float* v_b  = (const float*)d_in[7];
  const float* o_w  = (const float*)d_in[8];
  const float* o_b  = (const float*)d_in[9];
  float* out = (float*)d_out;

  char* ws = (char*)d_ws;
  const size_t MB = 1024 * 1024;
  const size_t szQKV = (size_t)BATCH * N * CI * sizeof(u16);  // 4 MB each
  u16* Qb  = (u16*)(ws);                      // 0..4MB (aliased by Ob later)
  u16* Kb  = (u16*)(ws + szQKV);              // 4..8MB
  u16* Vtb = (u16*)(ws + 2 * szQKV);          // 8..12MB
  u16* Wq  = (u16*)(ws + 3 * szQKV);          // 12..12.25MB
  u16* Wk  = Wq + (size_t)CI * C;
  u16* Wv  = Wk + (size_t)CI * C;
  u16* Wo  = Wv + (size_t)CI * C;
  u16* Opart = (u16*)(ws + 13 * MB);
  // split=8 needs 13 + 32 + 1 = 46MB of ws; fall back to 4 if tight
  const int split = (ws_size >= 46 * MB) ? 8 : 4;
  float2* ml = (float2*)(ws + 13 * MB + (size_t)split * szQKV);
  u16* Ob  = Qb;  // alias: Qb dead after attn

  const int kpb = N / split;
  const int grid_attn = 32 * BATCH * split;  // (N/128) * B * split
  const int cpx = grid_attn / 8;

  cvt_w<<<dim3((C * CI) / 256), 256, 0, stream>>>(q_w, k_w, v_w, o_w, Wq, Wk, Wv, Wo);
  proj_kernel<<<dim3(N / 64, BATCH), 256, 0, stream>>>(x, rgbd, Wq, Wk, Wv,
                                                       q_b, k_b, v_b, Qb, Kb, Vtb);
  attn_kernel<<<dim3(grid_attn), 256, 0, stream>>>(Qb, Kb, Vtb, Opart, ml, kpb, cpx);
  if (split == 8) {
    combine_kernel<8><<<dim3(BATCH * N * (CI / 8) / 256), 256, 0, stream>>>(Opart, ml, Ob);
  } else {
    combine_kernel<4><<<dim3(BATCH * N * (CI / 8) / 256), 256, 0, stream>>>(Opart, ml, Ob);
  }
  outproj_kernel<<<dim3(N / 64, BATCH), 256, 0, stream>>>(Ob, Wo, o_b, rgbd, out);
}